// Round 1
// baseline (2608.151 us; speedup 1.0000x reference)
//
#include <hip/hip_runtime.h>

// ---------------- problem constants (match reference) ----------------
constexpr int NUSERS = 500000;
constexpr int NITEMS = 100000;
constexpr int NNODES = NUSERS + NITEMS;   // 600000
constexpr int EDGES  = 1000000;
constexpr int DIM    = 32;
constexpr long long XSZ = (long long)NNODES * DIM;  // 19,200,000 floats = 76.8 MB

// ---------------- kernel 1: build x0 = concat(l2norm(user), l2norm(item)) ----
// 8 lanes per row, one float4 per lane. Also initializes acc (= d_out) with x0.
__global__ void compute_x_kernel(
    const float* __restrict__ user_w,
    const float* __restrict__ audio,
    const float* __restrict__ artist_w,
    const float* __restrict__ album_w,
    const int*   __restrict__ artist_ids,
    const int*   __restrict__ album_ids,
    float* __restrict__ x,
    float* __restrict__ acc)
{
    int t   = blockIdx.x * blockDim.x + threadIdx.x;
    int row = t >> 3;
    if (row >= NNODES) return;
    int c = (t & 7) << 2;  // float offset within the 32-wide row

    float4 v;
    if (row < NUSERS) {
        v = *(const float4*)(user_w + (long long)row * DIM + c);
    } else {
        int it = row - NUSERS;
        float4 a  = *(const float4*)(audio + (long long)it * DIM + c);
        int ar = artist_ids[it];
        int al = album_ids[it];
        float4 m1 = *(const float4*)(artist_w + (long long)ar * DIM + c);
        float4 m2 = *(const float4*)(album_w  + (long long)al * DIM + c);
        v.x = a.x + 0.5f * (m1.x + m2.x);
        v.y = a.y + 0.5f * (m1.y + m2.y);
        v.z = a.z + 0.5f * (m1.z + m2.z);
        v.w = a.w + 0.5f * (m1.w + m2.w);
    }

    float ss = v.x*v.x + v.y*v.y + v.z*v.z + v.w*v.w;
    // reduce across the 8 lanes owning this row (lanes row*8 .. row*8+7)
    ss += __shfl_xor(ss, 1);
    ss += __shfl_xor(ss, 2);
    ss += __shfl_xor(ss, 4);
    float s = 1.0f / fmaxf(sqrtf(ss), 1e-12f);
    v.x *= s; v.y *= s; v.z *= s; v.w *= s;

    long long o = (long long)row * DIM + c;
    *(float4*)(x   + o) = v;
    *(float4*)(acc + o) = v;
}

// ---------------- kernel 2: scatter one propagation layer ----------------
// y[dst] += w * x[src] over 2M directed edges (1M forward user->item,
// 1M reverse). Thread = (directed edge, float4 chunk): 16M threads.
__global__ void scatter_kernel(
    const float* __restrict__ x,
    float*       __restrict__ y,
    const int*   __restrict__ esrc,
    const int*   __restrict__ edst,
    const float* __restrict__ ew)
{
    int t = blockIdx.x * blockDim.x + threadIdx.x;
    int e = t >> 3;
    if (e >= 2 * EDGES) return;
    int c = (t & 7) << 2;

    int s, d; float w;
    if (e < EDGES) {
        s = esrc[e];
        d = edst[e] + NUSERS;
        w = ew[e];
    } else {
        int e2 = e - EDGES;
        s = edst[e2] + NUSERS;
        d = esrc[e2];
        w = ew[e2];
    }

    float4 v = *(const float4*)(x + (long long)s * DIM + c);
    float* yp = y + (long long)d * DIM + c;
    atomicAdd(yp + 0, w * v.x);
    atomicAdd(yp + 1, w * v.y);
    atomicAdd(yp + 2, w * v.z);
    atomicAdd(yp + 3, w * v.w);
}

// ---------------- kernel 3: acc += y (streaming, float4) ----------------
__global__ void acc_add_kernel(float* __restrict__ acc, const float* __restrict__ y)
{
    long long t = (long long)blockIdx.x * blockDim.x + threadIdx.x;
    long long i = t << 2;
    if (i >= XSZ) return;
    float4 a = *(float4*)(acc + i);
    float4 b = *(const float4*)(y + i);
    a.x += b.x; a.y += b.y; a.z += b.z; a.w += b.w;
    *(float4*)(acc + i) = a;
}

// ---------------- kernel 4: out = l2norm(acc/4) in place + loss scalar ------
__global__ void finalize_kernel(float* __restrict__ out)
{
    int t   = blockIdx.x * blockDim.x + threadIdx.x;
    if (t == 0) out[XSZ] = 0.0f;   // align_loss
    int row = t >> 3;
    if (row >= NNODES) return;
    int c = (t & 7) << 2;

    long long o = (long long)row * DIM + c;
    float4 v = *(float4*)(out + o);
    v.x *= 0.25f; v.y *= 0.25f; v.z *= 0.25f; v.w *= 0.25f;

    float ss = v.x*v.x + v.y*v.y + v.z*v.z + v.w*v.w;
    ss += __shfl_xor(ss, 1);
    ss += __shfl_xor(ss, 2);
    ss += __shfl_xor(ss, 4);
    float s = 1.0f / fmaxf(sqrtf(ss), 1e-12f);
    v.x *= s; v.y *= s; v.z *= s; v.w *= s;
    *(float4*)(out + o) = v;
}

// ---------------- host launch ----------------
extern "C" void kernel_launch(void* const* d_in, const int* in_sizes, int n_in,
                              void* d_out, int out_size, void* d_ws, size_t ws_size,
                              hipStream_t stream)
{
    const float* user_w     = (const float*)d_in[0];
    const float* audio      = (const float*)d_in[1];
    const float* artist_w   = (const float*)d_in[2];
    const float* album_w    = (const float*)d_in[3];
    const float* ew         = (const float*)d_in[4];
    const int*   artist_ids = (const int*)d_in[5];
    const int*   album_ids  = (const int*)d_in[6];
    const int*   esrc       = (const int*)d_in[7];
    const int*   edst       = (const int*)d_in[8];
    float* out = (float*)d_out;   // doubles as acc (exactly NNODES*32 + 1 loss)

    float* xA = (float*)d_ws;
    float* xB = xA + XSZ;         // needs 2 * 76.8 MB of workspace

    const int THR = 256;
    const int nt_rows  = NNODES * 8;          // 4.8M threads (row kernels)
    const int nt_scat  = 2 * EDGES * 8;       // 16M threads
    const int nt_add   = (int)(XSZ / 4);      // 4.8M threads

    // x0 + acc init
    compute_x_kernel<<<(nt_rows + THR - 1) / THR, THR, 0, stream>>>(
        user_w, audio, artist_w, album_w, artist_ids, album_ids, xA, out);

    float* cur = xA;
    float* nxt = xB;
    for (int layer = 0; layer < 3; ++layer) {
        hipMemsetAsync(nxt, 0, XSZ * sizeof(float), stream);
        scatter_kernel<<<(nt_scat + THR - 1) / THR, THR, 0, stream>>>(
            cur, nxt, esrc, edst, ew);
        acc_add_kernel<<<(nt_add + THR - 1) / THR, THR, 0, stream>>>(out, nxt);
        float* tmp = cur; cur = nxt; nxt = tmp;
    }

    finalize_kernel<<<(nt_rows + THR - 1) / THR, THR, 0, stream>>>(out);
}

// Round 2
// 537.307 us; speedup vs baseline: 4.8541x; 4.8541x over previous
//
#include <hip/hip_runtime.h>

// ---------------- problem constants (match reference) ----------------
constexpr int NUSERS = 500000;
constexpr int NITEMS = 100000;
constexpr int NNODES = NUSERS + NITEMS;   // 600000
constexpr int EDGES  = 1000000;
constexpr int DIM    = 32;
constexpr long long XSZ  = (long long)NNODES * DIM;  // 19.2M floats
constexpr long long USZ  = (long long)NUSERS * DIM;  // 16.0M floats
constexpr long long ITSZ = (long long)NITEMS * DIM;  //  3.2M floats
constexpr int NBI = (NITEMS + 1023) / 1024;   // 98  scan blocks (items)
constexpr int NBU = (NUSERS + 1023) / 1024;   // 489 scan blocks (users)

// ---------------- kernel: build x0 = concat(l2norm(user), l2norm(item)) ----
// 8 lanes per row, one float4 per lane. Also initializes acc (= d_out).
__global__ void compute_x_kernel(
    const float* __restrict__ user_w,
    const float* __restrict__ audio,
    const float* __restrict__ artist_w,
    const float* __restrict__ album_w,
    const int*   __restrict__ artist_ids,
    const int*   __restrict__ album_ids,
    float* __restrict__ x,
    float* __restrict__ acc)
{
    int t   = blockIdx.x * blockDim.x + threadIdx.x;
    int row = t >> 3;
    if (row >= NNODES) return;
    int c = (t & 7) << 2;

    float4 v;
    if (row < NUSERS) {
        v = *(const float4*)(user_w + (long long)row * DIM + c);
    } else {
        int it = row - NUSERS;
        float4 a  = *(const float4*)(audio + (long long)it * DIM + c);
        int ar = artist_ids[it];
        int al = album_ids[it];
        float4 m1 = *(const float4*)(artist_w + (long long)ar * DIM + c);
        float4 m2 = *(const float4*)(album_w  + (long long)al * DIM + c);
        v.x = a.x + 0.5f * (m1.x + m2.x);
        v.y = a.y + 0.5f * (m1.y + m2.y);
        v.z = a.z + 0.5f * (m1.z + m2.z);
        v.w = a.w + 0.5f * (m1.w + m2.w);
    }

    float ss = v.x*v.x + v.y*v.y + v.z*v.z + v.w*v.w;
    ss += __shfl_xor(ss, 1);
    ss += __shfl_xor(ss, 2);
    ss += __shfl_xor(ss, 4);
    float s = 1.0f / fmaxf(sqrtf(ss), 1e-12f);
    v.x *= s; v.y *= s; v.z *= s; v.w *= s;

    long long o = (long long)row * DIM + c;
    *(float4*)(x   + o) = v;
    *(float4*)(acc + o) = v;
}

// ---------------- CSR build ----------------
__global__ void count_deg_kernel(const int* __restrict__ esrc,
                                 const int* __restrict__ edst,
                                 int* __restrict__ degU, int* __restrict__ degI)
{
    int e = blockIdx.x * blockDim.x + threadIdx.x;
    if (e >= EDGES) return;
    atomicAdd(&degU[esrc[e]], 1);
    atomicAdd(&degI[edst[e]], 1);
}

// exclusive scan, pass 1: per-block (1024 elems) scan + block totals
__global__ void scan1_kernel(const int* __restrict__ in, int* __restrict__ out,
                             int* __restrict__ bsum, int n)
{
    __shared__ int lds[256];
    int tid  = threadIdx.x;
    int base = blockIdx.x * 1024 + tid * 4;
    int v0=0,v1=0,v2=0,v3=0;
    if (base + 0 < n) v0 = in[base + 0];
    if (base + 1 < n) v1 = in[base + 1];
    if (base + 2 < n) v2 = in[base + 2];
    if (base + 3 < n) v3 = in[base + 3];
    int t = v0 + v1 + v2 + v3;
    lds[tid] = t; __syncthreads();
    for (int ofs = 1; ofs < 256; ofs <<= 1) {
        int add = (tid >= ofs) ? lds[tid - ofs] : 0;
        __syncthreads();
        lds[tid] += add;
        __syncthreads();
    }
    int excl = lds[tid] - t;
    if (base + 0 < n) out[base + 0] = excl;  excl += v0;
    if (base + 1 < n) out[base + 1] = excl;  excl += v1;
    if (base + 2 < n) out[base + 2] = excl;  excl += v2;
    if (base + 3 < n) out[base + 3] = excl;
    if (tid == 255) bsum[blockIdx.x] = lds[255];
}

// pass 2: single 512-thread block, exclusive scan of block sums in place (n<=512)
__global__ void scan2_kernel(int* __restrict__ bsum, int n)
{
    __shared__ int lds[512];
    int tid = threadIdx.x;
    int t = (tid < n) ? bsum[tid] : 0;
    lds[tid] = t; __syncthreads();
    for (int ofs = 1; ofs < 512; ofs <<= 1) {
        int add = (tid >= ofs) ? lds[tid - ofs] : 0;
        __syncthreads();
        lds[tid] += add;
        __syncthreads();
    }
    if (tid < n) bsum[tid] = lds[tid] - t;
}

// pass 3: add block offsets; write sentinel out[n] = total (known = EDGES)
__global__ void scan3_kernel(int* __restrict__ out, const int* __restrict__ bsum,
                             int n, int total)
{
    int base = blockIdx.x * 1024 + threadIdx.x * 4;
    int add = bsum[blockIdx.x];
    if (base + 0 < n) out[base + 0] += add;
    if (base + 1 < n) out[base + 1] += add;
    if (base + 2 < n) out[base + 2] += add;
    if (base + 3 < n) out[base + 3] += add;
    if (blockIdx.x == 0 && threadIdx.x == 0) out[n] = total;
}

// cursors = offsets copy (items then users concatenated)
__global__ void copy_cur_kernel(const int* __restrict__ offsI, const int* __restrict__ offsU,
                                int* __restrict__ curI, int* __restrict__ curU)
{
    int i = blockIdx.x * blockDim.x + threadIdx.x;
    if (i < NITEMS) curI[i] = offsI[i];
    else if (i < NITEMS + NUSERS) curU[i - NITEMS] = offsU[i - NITEMS];
}

__global__ void fill_csr_kernel(const int* __restrict__ esrc, const int* __restrict__ edst,
                                const float* __restrict__ ew,
                                int* __restrict__ curI, int* __restrict__ curU,
                                int* __restrict__ srcI, float* __restrict__ wI,
                                int* __restrict__ srcU, float* __restrict__ wU)
{
    int e = blockIdx.x * blockDim.x + threadIdx.x;
    if (e >= EDGES) return;
    int u = esrc[e], it = edst[e];
    float w = ew[e];
    int pi = atomicAdd(&curI[it], 1);
    srcI[pi] = u;  wI[pi] = w;
    int pu = atomicAdd(&curU[u], 1);
    srcU[pu] = it; wU[pu] = w;
}

// ---------------- gather layer: y[v] = sum w * xsrc[nbr]; x_new = y; acc += y
// 8 lanes per dst node, float4 chunk each.
__global__ void gather_kernel(const int* __restrict__ offs,
                              const int* __restrict__ srcs,
                              const float* __restrict__ ws,
                              const float* __restrict__ xsrc,
                              float* __restrict__ xdst,
                              float* __restrict__ acc, int n)
{
    int t = blockIdx.x * blockDim.x + threadIdx.x;
    int v = t >> 3;
    if (v >= n) return;
    int c = (t & 7) << 2;

    int b = offs[v], e = offs[v + 1];
    float4 sum = {0.f, 0.f, 0.f, 0.f};
    for (int k = b; k < e; ++k) {
        int s   = srcs[k];
        float w = ws[k];
        float4 xv = *(const float4*)(xsrc + (long long)s * DIM + c);
        sum.x += w * xv.x;
        sum.y += w * xv.y;
        sum.z += w * xv.z;
        sum.w += w * xv.w;
    }
    long long o = (long long)v * DIM + c;
    *(float4*)(xdst + o) = sum;
    float4 a = *(float4*)(acc + o);
    a.x += sum.x; a.y += sum.y; a.z += sum.z; a.w += sum.w;
    *(float4*)(acc + o) = a;
}

// ---------------- finalize: out = l2norm(acc/4) + loss scalar ----------------
__global__ void finalize_kernel(float* __restrict__ out)
{
    int t = blockIdx.x * blockDim.x + threadIdx.x;
    if (t == 0) out[XSZ] = 0.0f;
    int row = t >> 3;
    if (row >= NNODES) return;
    int c = (t & 7) << 2;

    long long o = (long long)row * DIM + c;
    float4 v = *(float4*)(out + o);
    v.x *= 0.25f; v.y *= 0.25f; v.z *= 0.25f; v.w *= 0.25f;

    float ss = v.x*v.x + v.y*v.y + v.z*v.z + v.w*v.w;
    ss += __shfl_xor(ss, 1);
    ss += __shfl_xor(ss, 2);
    ss += __shfl_xor(ss, 4);
    float s = 1.0f / fmaxf(sqrtf(ss), 1e-12f);
    v.x *= s; v.y *= s; v.z *= s; v.w *= s;
    *(float4*)(out + o) = v;
}

// ---------------- host launch ----------------
extern "C" void kernel_launch(void* const* d_in, const int* in_sizes, int n_in,
                              void* d_out, int out_size, void* d_ws, size_t ws_size,
                              hipStream_t stream)
{
    const float* user_w     = (const float*)d_in[0];
    const float* audio      = (const float*)d_in[1];
    const float* artist_w   = (const float*)d_in[2];
    const float* album_w    = (const float*)d_in[3];
    const float* ew         = (const float*)d_in[4];
    const int*   artist_ids = (const int*)d_in[5];
    const int*   album_ids  = (const int*)d_in[6];
    const int*   esrc       = (const int*)d_in[7];
    const int*   edst       = (const int*)d_in[8];
    float* out = (float*)d_out;   // acc lives here (NNODES*32 floats + loss)

    // workspace layout (~110.4 MB)
    float* x     = (float*)d_ws;           // XSZ floats
    float* tmpIt = x + XSZ;                // ITSZ floats (item-row snapshot)
    int*   offsI = (int*)(tmpIt + ITSZ);   // NITEMS+1
    int*   offsU = offsI + (NITEMS + 1);   // NUSERS+1
    int*   curI  = offsU + (NUSERS + 1);   // NITEMS   (also degree scratch)
    int*   curU  = curI + NITEMS;          // NUSERS
    int*   srcI  = curU + NUSERS;          // EDGES (user id per item-CSR slot)
    float* wI    = (float*)(srcI + EDGES); // EDGES
    int*   srcU  = (int*)(wI + EDGES);     // EDGES (item id per user-CSR slot)
    float* wU    = (float*)(srcU + EDGES); // EDGES
    int*   bsumI = (int*)(wU + EDGES);     // NBI
    int*   bsumU = bsumI + NBI;            // NBU

    const int THR = 256;
    const int g_edges = (EDGES + THR - 1) / THR;

    // ---- CSR build ----
    hipMemsetAsync(curI, 0, (size_t)(NITEMS + NUSERS) * sizeof(int), stream);
    count_deg_kernel<<<g_edges, THR, 0, stream>>>(esrc, edst, curU, curI);

    scan1_kernel<<<NBI, 256, 0, stream>>>(curI, offsI, bsumI, NITEMS);
    scan2_kernel<<<1, 512, 0, stream>>>(bsumI, NBI);
    scan3_kernel<<<NBI, 256, 0, stream>>>(offsI, bsumI, NITEMS, EDGES);

    scan1_kernel<<<NBU, 256, 0, stream>>>(curU, offsU, bsumU, NUSERS);
    scan2_kernel<<<1, 512, 0, stream>>>(bsumU, NBU);
    scan3_kernel<<<NBU, 256, 0, stream>>>(offsU, bsumU, NUSERS, EDGES);

    copy_cur_kernel<<<(NITEMS + NUSERS + THR - 1) / THR, THR, 0, stream>>>(
        offsI, offsU, curI, curU);
    fill_csr_kernel<<<g_edges, THR, 0, stream>>>(
        esrc, edst, ew, curI, curU, srcI, wI, srcU, wU);

    // ---- x0 + acc init ----
    const int nt_rows = NNODES * 8;
    compute_x_kernel<<<(nt_rows + THR - 1) / THR, THR, 0, stream>>>(
        user_w, audio, artist_w, album_w, artist_ids, album_ids, x, out);

    // ---- 3 propagation layers, in-place x with item snapshot ----
    float* xItems = x + USZ;
    for (int layer = 0; layer < 3; ++layer) {
        hipMemcpyAsync(tmpIt, xItems, ITSZ * sizeof(float),
                       hipMemcpyDeviceToDevice, stream);
        // items <- sum over their users (reads user rows of x, still old)
        gather_kernel<<<(NITEMS * 8 + THR - 1) / THR, THR, 0, stream>>>(
            offsI, srcI, wI, x, xItems, out + USZ, NITEMS);
        // users <- sum over their items (reads snapshot of old item rows)
        gather_kernel<<<(NUSERS * 8 + THR - 1) / THR, THR, 0, stream>>>(
            offsU, srcU, wU, tmpIt, x, out, NUSERS);
    }

    finalize_kernel<<<(nt_rows + THR - 1) / THR, THR, 0, stream>>>(out);
}